// Round 10
// baseline (47.372 us; speedup 1.0000x reference)
//
#include <hip/hip_runtime.h>

#define KC 256                   // codebook size
#define NROWS (8*64*64*64/4)     // 524288 rows of dim 4
#define RPT 2                    // rows per thread
#define TPB 256                  // threads per block
#define NB (NROWS/(TPB*RPT))     // 1024 blocks
#define NG (KC/4)                // 64 chunks of 4 centers

// DIAGNOSTIC ROUND: scan the codebook TWICE (fwd then bwd). Second pass can
// never strictly exceed the running max -> output identical to one pass.
// Purpose: separate fixed dispatch overhead from work-scaling time, and push
// our dispatch above the harness's 39us fills so rocprof shows its counters.
__global__ __launch_bounds__(TPB) void vq_main(const float* __restrict__ x,
                                               const float* __restrict__ center,
                                               float* __restrict__ out) {
    __shared__ float4 smh4[NG];    // -0.5*||c||^2, packed 4 per float4

    const int tid = threadIdx.x;
    {
        float4 c = reinterpret_cast<const float4*>(center)[tid];
        reinterpret_cast<float*>(smh4)[tid] =
            -0.5f * (c.x * c.x + c.y * c.y + c.z * c.z + c.w * c.w);
    }
    __syncthreads();

    const int base = blockIdx.x * (TPB * RPT) + tid;
    const float4* x4 = reinterpret_cast<const float4*>(x);
    const float4 xa = x4[base];
    const float4 xb = x4[base + TPB];

    float bpa = -__builtin_inff(), bpb = -__builtin_inff();
    int bca = 0, bcb = 0;          // winning chunk ids

    for (int pass = 0; pass < 2; ++pass) {
#pragma unroll 2
        for (int gi = 0; gi < NG; ++gi) {
            const int g = pass ? (NG - 1 - gi) : gi;   // bwd order on pass 1 (anti-CSE)
            // 16 consecutive codebook floats, uniform index -> s_load_dwordx16.
            float cv[16];
#pragma unroll
            for (int j = 0; j < 16; ++j) cv[j] = center[16 * g + j];
            const float4 m = smh4[g];  // uniform ds_read_b128 broadcast

            float pa0, pa1, pa2, pa3, pb0, pb1, pb2, pb3;
#pragma unroll
            for (int j = 0; j < 4; ++j) {
                const float cx = cv[4*j+0], cy = cv[4*j+1];
                const float cz = cv[4*j+2], cw = cv[4*j+3];
                const float mh = (j == 0) ? m.x : (j == 1) ? m.y : (j == 2) ? m.z : m.w;
                float t = fmaf(xa.x, cx, mh);          // same fma order as all
                t = fmaf(xa.y, cy, t);                 // previous passing rounds
                t = fmaf(xa.z, cz, t);
                t = fmaf(xa.w, cw, t);
                float u = fmaf(xb.x, cx, mh);
                u = fmaf(xb.y, cy, u);
                u = fmaf(xb.z, cz, u);
                u = fmaf(xb.w, cw, u);
                if (j == 0) { pa0 = t; pb0 = u; }
                else if (j == 1) { pa1 = t; pb1 = u; }
                else if (j == 2) { pa2 = t; pb2 = u; }
                else { pa3 = t; pb3 = u; }
            }
            const float ma = fmaxf(fmaxf(fmaxf(pa0, pa1), pa2), pa3);
            const float mb = fmaxf(fmaxf(fmaxf(pb0, pb1), pb2), pb3);
            // strict '>': earliest chunk in pass-0 order wins ties
            const bool ta = ma > bpa;
            bpa = ta ? ma : bpa;
            bca = ta ? g : bca;
            const bool tb = mb > bpb;
            bpb = tb ? mb : bpb;
            bcb = tb ? g : bcb;
        }
    }

    // Epilogue: same bit-exact within-chunk resolution as round 9 (passing).
    auto resolve = [&](const float4 xv, const int bc) -> float4 {
        float cv[16];
#pragma unroll
        for (int j = 0; j < 16; ++j) cv[j] = center[16 * bc + j];  // L1-resident
        const float4 m = smh4[bc];   // same bits as main loop
        float p[4];
#pragma unroll
        for (int j = 0; j < 4; ++j) {
            const float cx = cv[4*j+0], cy = cv[4*j+1];
            const float cz = cv[4*j+2], cw = cv[4*j+3];
            const float mh = (j == 0) ? m.x : (j == 1) ? m.y : (j == 2) ? m.z : m.w;
            float t = fmaf(xv.x, cx, mh);
            t = fmaf(xv.y, cy, t);
            t = fmaf(xv.z, cz, t);
            t = fmaf(xv.w, cw, t);
            p[j] = t;
        }
        const float mx = fmaxf(fmaxf(fmaxf(p[0], p[1]), p[2]), p[3]);
        float wx = cv[12], wy = cv[13], wz = cv[14], ww = cv[15];
        if (p[2] == mx) { wx = cv[8];  wy = cv[9];  wz = cv[10]; ww = cv[11]; }
        if (p[1] == mx) { wx = cv[4];  wy = cv[5];  wz = cv[6];  ww = cv[7];  }
        if (p[0] == mx) { wx = cv[0];  wy = cv[1];  wz = cv[2];  ww = cv[3];  }
        return make_float4(wx, wy, wz, ww);
    };

    reinterpret_cast<float4*>(out)[base]       = resolve(xa, bca);
    reinterpret_cast<float4*>(out)[base + TPB] = resolve(xb, bcb);
}

extern "C" void kernel_launch(void* const* d_in, const int* in_sizes, int n_in,
                              void* d_out, int out_size, void* d_ws, size_t ws_size,
                              hipStream_t stream) {
    const float* x      = (const float*)d_in[0];
    const float* center = (const float*)d_in[1];
    float* out = (float*)d_out;

    vq_main<<<NB, TPB, 0, stream>>>(x, center, out);
}

// Round 11
// 26.016 us; speedup vs baseline: 1.8209x; 1.8209x over previous
//
#include <hip/hip_runtime.h>

typedef float fv2 __attribute__((ext_vector_type(2)));

#define KC 256                   // codebook size
#define NROWS (8*64*64*64/4)     // 524288 rows of dim 4
#define RPT 4                    // rows per thread
#define TPB 256                  // threads per block
#define NB (NROWS/(TPB*RPT))     // 512 blocks
#define NG (KC/4)                // 64 chunks of 4 centers

// argmax_k (x.c_k - 0.5*||c_k||^2) == argmin_k ||x - c_k||^2.
// Chunk-max main loop (cmp+sel once per 4-center chunk per row); rows packed
// pairwise -> v_pk_fma_f32 / v_pk_max_f32 (per-half bit-identical to scalar
// v_fma/v_max). Within-chunk k recovered by the self-contained bit-exact
// resolve epilogue (round-9 structure, proven absmax 0).
__global__ __launch_bounds__(TPB) void vq_main(const float* __restrict__ x,
                                               const float* __restrict__ center,
                                               float* __restrict__ out) {
    __shared__ float4 smh4[NG];    // -0.5*||c||^2, packed 4 per float4

    const int tid = threadIdx.x;
    {
        float4 c = reinterpret_cast<const float4*>(center)[tid];
        reinterpret_cast<float*>(smh4)[tid] =
            -0.5f * (c.x * c.x + c.y * c.y + c.z * c.z + c.w * c.w);
    }
    __syncthreads();

    const int base = blockIdx.x * (TPB * RPT) + tid;
    const float4* x4 = reinterpret_cast<const float4*>(x);
    const float4 xr0 = x4[base];
    const float4 xr1 = x4[base + TPB];
    const float4 xr2 = x4[base + 2 * TPB];
    const float4 xr3 = x4[base + 3 * TPB];

    // Row-pair packs (built once): half .x = even row, half .y = odd row.
    const fv2 X01x = {xr0.x, xr1.x}, X01y = {xr0.y, xr1.y},
              X01z = {xr0.z, xr1.z}, X01w = {xr0.w, xr1.w};
    const fv2 X23x = {xr2.x, xr3.x}, X23y = {xr2.y, xr3.y},
              X23z = {xr2.z, xr3.z}, X23w = {xr2.w, xr3.w};

    float bp0 = -__builtin_inff(), bp1 = -__builtin_inff();
    float bp2 = -__builtin_inff(), bp3 = -__builtin_inff();
    int bc0 = 0, bc1 = 0, bc2 = 0, bc3 = 0;   // winning chunk ids

#pragma unroll 2
    for (int g = 0; g < NG; ++g) {
        // 16 consecutive codebook floats, uniform index -> s_load_dwordx16.
        float cv[16];
#pragma unroll
        for (int j = 0; j < 16; ++j) cv[j] = center[16 * g + j];
        const float4 m = smh4[g];  // uniform ds_read_b128 broadcast (VGPR)

        fv2 q01[4], q23[4];
#pragma unroll
        for (int j = 0; j < 4; ++j) {
            const float cx = cv[4*j+0], cy = cv[4*j+1];
            const float cz = cv[4*j+2], cw = cv[4*j+3];
            const float mh = (j == 0) ? m.x : (j == 1) ? m.y : (j == 2) ? m.z : m.w;
            const fv2 Cx = {cx, cx}, Cy = {cy, cy}, Cz = {cz, cz}, Cw = {cw, cw};
            const fv2 MH = {mh, mh};
            // Same per-row fma chain order as every passing round.
            fv2 t = __builtin_elementwise_fma(X01x, Cx, MH);
            t = __builtin_elementwise_fma(X01y, Cy, t);
            t = __builtin_elementwise_fma(X01z, Cz, t);
            t = __builtin_elementwise_fma(X01w, Cw, t);
            q01[j] = t;
            fv2 u = __builtin_elementwise_fma(X23x, Cx, MH);
            u = __builtin_elementwise_fma(X23y, Cy, u);
            u = __builtin_elementwise_fma(X23z, Cz, u);
            u = __builtin_elementwise_fma(X23w, Cw, u);
            q23[j] = u;
        }
        // Packed chunk-max trees (v_pk_max_f32), per-half == fmaxf chain.
        const fv2 m01 = __builtin_elementwise_max(
            __builtin_elementwise_max(q01[0], q01[1]),
            __builtin_elementwise_max(q01[2], q01[3]));
        const fv2 m23 = __builtin_elementwise_max(
            __builtin_elementwise_max(q23[0], q23[1]),
            __builtin_elementwise_max(q23[2], q23[3]));

        // strict '>': earliest chunk wins ties (argmin-first semantics)
        const bool t0 = m01.x > bp0; bp0 = t0 ? m01.x : bp0; bc0 = t0 ? g : bc0;
        const bool t1 = m01.y > bp1; bp1 = t1 ? m01.y : bp1; bc1 = t1 ? g : bc1;
        const bool t2 = m23.x > bp2; bp2 = t2 ? m23.x : bp2; bc2 = t2 ? g : bc2;
        const bool t3 = m23.y > bp3; bp3 = t3 ? m23.y : bp3; bc3 = t3 ? g : bc3;
    }

    // Epilogue (self-contained, round-9 proven): recompute the winning chunk's
    // 4 scores from the SAME mh bits (smh4) with the same scalar fma chain
    // (== pk per-half bits), take its local max, pick lowest matching j.
    auto resolve = [&](const float4 xv, const int bc) -> float4 {
        float cv[16];
#pragma unroll
        for (int j = 0; j < 16; ++j) cv[j] = center[16 * bc + j];  // L1-resident
        const float4 m = smh4[bc];   // same bits as main loop
        float p[4];
#pragma unroll
        for (int j = 0; j < 4; ++j) {
            const float cx = cv[4*j+0], cy = cv[4*j+1];
            const float cz = cv[4*j+2], cw = cv[4*j+3];
            const float mh = (j == 0) ? m.x : (j == 1) ? m.y : (j == 2) ? m.z : m.w;
            float t = fmaf(xv.x, cx, mh);
            t = fmaf(xv.y, cy, t);
            t = fmaf(xv.z, cz, t);
            t = fmaf(xv.w, cw, t);
            p[j] = t;
        }
        const float mx = fmaxf(fmaxf(fmaxf(p[0], p[1]), p[2]), p[3]);
        float wx = cv[12], wy = cv[13], wz = cv[14], ww = cv[15];
        if (p[2] == mx) { wx = cv[8];  wy = cv[9];  wz = cv[10]; ww = cv[11]; }
        if (p[1] == mx) { wx = cv[4];  wy = cv[5];  wz = cv[6];  ww = cv[7];  }
        if (p[0] == mx) { wx = cv[0];  wy = cv[1];  wz = cv[2];  ww = cv[3];  }
        return make_float4(wx, wy, wz, ww);
    };

    float4* o4 = reinterpret_cast<float4*>(out);
    o4[base]           = resolve(xr0, bc0);
    o4[base + TPB]     = resolve(xr1, bc1);
    o4[base + 2 * TPB] = resolve(xr2, bc2);
    o4[base + 3 * TPB] = resolve(xr3, bc3);
}

extern "C" void kernel_launch(void* const* d_in, const int* in_sizes, int n_in,
                              void* d_out, int out_size, void* d_ws, size_t ws_size,
                              hipStream_t stream) {
    const float* x      = (const float*)d_in[0];
    const float* center = (const float*)d_in[1];
    float* out = (float*)d_out;

    vq_main<<<NB, TPB, 0, stream>>>(x, center, out);
}